// Round 3
// baseline (923.002 us; speedup 1.0000x reference)
//
#include <hip/hip_runtime.h>
#include <hip/hip_bf16.h>
#include <type_traits>
#include <utility>

// Problem: B=32, P=4, N=1024, C=384.
// softmax over a size-1 axis == 1.0, so:
//   cv[b,p,:]  = (sum_n x[b,p,n,:]) @ Wk + N*bk          (fp32, exact)
//   out        = (relu(x@Wv + bv) * cv) @ Wp + bp        (bf16 MFMA, fused)
#define C_    384
#define N_    1024
#define G_    128          // B*P groups
#define QKVD  769

typedef float  f32x4 __attribute__((ext_vector_type(4)));
typedef short  s16x8 __attribute__((ext_vector_type(8)));
typedef __bf16 b16x8 __attribute__((ext_vector_type(8)));

template <typename V, typename = void>
struct mfma_takes : std::false_type {};
template <typename V>
struct mfma_takes<V, std::void_t<decltype(__builtin_amdgcn_mfma_f32_16x16x32_bf16(
    std::declval<V>(), std::declval<V>(), std::declval<f32x4>(), 0, 0, 0))>>
    : std::true_type {};

using frag_t = std::conditional_t<mfma_takes<s16x8>::value, s16x8, b16x8>;

template <typename V>
__device__ __forceinline__ f32x4 mfma_bf16(V a, V b, f32x4 c) {
  return __builtin_amdgcn_mfma_f32_16x16x32_bf16(a, b, c, 0, 0, 0);
}

__device__ __forceinline__ unsigned short f2bf(float f) {
  union { float f; unsigned u; } v; v.f = f;
  unsigned r = v.u + 0x7fffu + ((v.u >> 16) & 1u);   // RNE
  return (unsigned short)(r >> 16);
}
__device__ __forceinline__ unsigned pack2(float lo, float hi) {
  return (unsigned)f2bf(lo) | ((unsigned)f2bf(hi) << 16);
}

// ---------------- K1: xsum[g][c] = sum_n x[g][n][c]  (float4, LDS-reduced) ----------------
// 1024 blocks x 384 thr; block = 128 rows; thread: 32 rows x 4 cols.
__global__ __launch_bounds__(384) void k_xsum(const float* __restrict__ x,
                                              float* __restrict__ xsum) {
  __shared__ float sh[4][C_];
  const int tid = threadIdx.x;
  const int c4  = (tid % 96) * 4;
  const int rg  = tid / 96;            // 0..3
  const int b   = blockIdx.x;          // 1024
  const int g   = b >> 3;
  const float* p = x + ((size_t)b * 128 + (size_t)rg * 32) * C_ + c4;
  f32x4 s = {0.f, 0.f, 0.f, 0.f};
#pragma unroll 8
  for (int r = 0; r < 32; ++r) {
    float4 v = *(const float4*)(p + (size_t)r * C_);
    s.x += v.x; s.y += v.y; s.z += v.z; s.w += v.w;
  }
  *(f32x4*)&sh[rg][c4] = s;
  __syncthreads();
  if (rg == 0) {
#pragma unroll
    for (int j = 0; j < 4; ++j) {
      float v = sh[0][c4 + j] + sh[1][c4 + j] + sh[2][c4 + j] + sh[3][c4 + j];
      atomicAdd(&xsum[g * C_ + c4 + j], v);
    }
  }
}

// ---------------- K2: cv[g][c] = xsum[g]@Wk[:,c] + N*bk[c] ----------------
__global__ void k_cv(const float* __restrict__ xsum, const float* __restrict__ w_qkv,
                     const float* __restrict__ b_qkv, float* __restrict__ cv) {
  __shared__ float xs[C_];
  int g = blockIdx.x, c = threadIdx.x;   // 384 threads
  xs[c] = xsum[g * C_ + c];
  __syncthreads();
  float acc = 0.f;
#pragma unroll 4
  for (int k = 0; k < C_; ++k) acc += xs[k] * w_qkv[k * QKVD + 1 + c];
  cv[g * C_ + c] = acc + (float)N_ * b_qkv[1 + c];
}

// ------- K3: pack Wv (w_qkv[:,385:769]) and Wp (w_proj) as bf16 frag-major -------
// entry (kk,nf,lane) -> 8 bf16 = B[k = kk*32+(lane>>4)*8 + j][n = nf*16+(lane&15)]
__global__ void k_pack(const float* __restrict__ w_qkv, const float* __restrict__ w_proj,
                       unsigned short* __restrict__ pWv, unsigned short* __restrict__ pWp) {
  int bid = blockIdx.x;
  int mat = bid / 288;             // 0: Wv, 1: Wp    (288 = 12 kk * 24 nf)
  int r   = bid % 288;
  int kk = r / 24, nf = r % 24;
  int lane = threadIdx.x;          // 64
  int kbase = kk * 32 + (lane >> 4) * 8;
  int n = nf * 16 + (lane & 15);
  unsigned v[4];
#pragma unroll
  for (int jj = 0; jj < 4; ++jj) {
    int k0 = kbase + jj * 2;
    float f0 = mat ? w_proj[(size_t)k0 * C_ + n]       : w_qkv[(size_t)k0 * QKVD + 385 + n];
    float f1 = mat ? w_proj[(size_t)(k0 + 1) * C_ + n] : w_qkv[(size_t)(k0 + 1) * QKVD + 385 + n];
    v[jj] = (unsigned)f2bf(f0) | ((unsigned)f2bf(f1) << 16);
  }
  unsigned short* dst = (mat ? pWp : pWv) + ((size_t)r * 64 + lane) * 8;
  uint4 w; w.x = v[0]; w.y = v[1]; w.z = v[2]; w.w = v[3];
  *(uint4*)dst = w;
}

// ---------------- K4: fused, pipelined over 8 tiles of 32 rows ----------------
// 512 blocks x 512 thr (8 waves). Block owns 256 rows (one group g=blockIdx>>2).
// Wave w: 32 rows x cols [w*48, w*48+48). Double-buffered LDS x-tile, T14 prefetch.
__global__ __launch_bounds__(512, 4) void k_fused(
    const float* __restrict__ x, const unsigned short* __restrict__ pWv,
    const unsigned short* __restrict__ pWp, const float* __restrict__ cv,
    const float* __restrict__ b_qkv, const float* __restrict__ b_proj,
    float* __restrict__ out) {
  __shared__ __align__(16) char tile[2][32 * 768];   // 2 x (32 rows x 384 bf16), XOR-swizzled
  __shared__ float cv_l[C_], bv_l[C_], bp_l[C_];

  const int tid  = threadIdx.x;
  const int lane = tid & 63;
  const int wv   = tid >> 6;                 // 0..7
  const int g    = blockIdx.x >> 2;
  const size_t blockRow0 = (size_t)blockIdx.x * 256;
  const float* xblk = x + blockRow0 * C_;

  for (int c = tid; c < C_; c += 512) {
    cv_l[c] = cv[g * C_ + c];
    bv_l[c] = b_qkv[1 + C_ + c];
    bp_l[c] = b_proj[c];
  }

  // thread's 3 bf16 16B-chunks per tile: chunk c = tid + j*512 (j=0..2)
  // fp32 source: floats [c*8, c*8+8); LDS dest: row=c/48, off=(c%48)*16, XOR swizzle
  float4 pf[6];
#define LOADT(xt)                                                         \
  _Pragma("unroll") for (int j = 0; j < 3; ++j) {                         \
    pf[2 * j]     = *(const float4*)((xt) + ((size_t)tid + j * 512) * 8); \
    pf[2 * j + 1] = *(const float4*)((xt) + ((size_t)tid + j * 512) * 8 + 4); \
  }
#define STAGET(buf)                                                       \
  _Pragma("unroll") for (int j = 0; j < 3; ++j) {                         \
    int ch  = tid + j * 512;                                              \
    int row = ch / 48;                                                    \
    int off = (ch % 48) * 16;                                             \
    uint4 w;                                                              \
    w.x = pack2(pf[2 * j].x, pf[2 * j].y);                                \
    w.y = pack2(pf[2 * j].z, pf[2 * j].w);                                \
    w.z = pack2(pf[2 * j + 1].x, pf[2 * j + 1].y);                        \
    w.w = pack2(pf[2 * j + 1].z, pf[2 * j + 1].w);                        \
    *(uint4*)(tile[buf] + row * 768 + (off ^ ((row & 7) << 4))) = w;      \
  }

  // prologue: stage tile 0
  LOADT(xblk);
  STAGET(0);
  __syncthreads();

  const f32x4 zero = {0.f, 0.f, 0.f, 0.f};

#pragma unroll 1
  for (int t = 0; t < 8; ++t) {
    const int cur = t & 1;

    // T14: issue next tile's global loads NOW (consumed after GEMM2)
    if (t < 7) { LOADT(xblk + (size_t)(t + 1) * 32 * C_); }

    // ---- GEMM1: value = x @ Wv ----
    f32x4 acc[2][3];
#pragma unroll
    for (int m = 0; m < 2; ++m)
#pragma unroll
      for (int n = 0; n < 3; ++n) acc[m][n] = zero;

    for (int kk = 0; kk < 12; ++kk) {
      frag_t A[2], Bv[3];
      int kb2 = (kk * 32 + (lane >> 4) * 8) * 2;
#pragma unroll
      for (int m = 0; m < 2; ++m) {
        int row = m * 16 + (lane & 15);
        A[m] = *(const frag_t*)(tile[cur] + ((row * 768 + kb2) ^ ((row & 7) << 4)));
      }
      const unsigned short* bp_ = pWv + ((size_t)(kk * 24 + wv * 3) * 64 + lane) * 8;
#pragma unroll
      for (int n = 0; n < 3; ++n) Bv[n] = *(const frag_t*)(bp_ + (size_t)n * 64 * 8);
#pragma unroll
      for (int m = 0; m < 2; ++m)
#pragma unroll
        for (int n = 0; n < 3; ++n) acc[m][n] = mfma_bf16(A[m], Bv[n], acc[m][n]);
    }
    __syncthreads();   // all waves done reading x tile

    // ---- epilogue1: gated = relu(value + bv) * cv -> bf16 -> same buffer ----
#pragma unroll
    for (int m = 0; m < 2; ++m) {
#pragma unroll
      for (int n = 0; n < 3; ++n) {
        int col = wv * 48 + n * 16 + (lane & 15);
        float cvv = cv_l[col], bvv = bv_l[col];
#pragma unroll
        for (int r = 0; r < 4; ++r) {
          int row = m * 16 + (lane >> 4) * 4 + r;   // verified C/D layout
          float val = fmaxf(acc[m][n][r] + bvv, 0.f) * cvv;
          *(unsigned short*)(tile[cur] + ((row * 768 + col * 2) ^ ((row & 7) << 4))) = f2bf(val);
        }
      }
    }
    __syncthreads();   // gated tile complete

    // ---- GEMM2: out = gated @ Wp ----
#pragma unroll
    for (int m = 0; m < 2; ++m)
#pragma unroll
      for (int n = 0; n < 3; ++n) acc[m][n] = zero;

    for (int kk = 0; kk < 12; ++kk) {
      frag_t A[2], Bv[3];
      int kb2 = (kk * 32 + (lane >> 4) * 8) * 2;
#pragma unroll
      for (int m = 0; m < 2; ++m) {
        int row = m * 16 + (lane & 15);
        A[m] = *(const frag_t*)(tile[cur] + ((row * 768 + kb2) ^ ((row & 7) << 4)));
      }
      const unsigned short* bp_ = pWp + ((size_t)(kk * 24 + wv * 3) * 64 + lane) * 8;
#pragma unroll
      for (int n = 0; n < 3; ++n) Bv[n] = *(const frag_t*)(bp_ + (size_t)n * 64 * 8);
#pragma unroll
      for (int m = 0; m < 2; ++m)
#pragma unroll
        for (int n = 0; n < 3; ++n) acc[m][n] = mfma_bf16(A[m], Bv[n], acc[m][n]);
    }

    // ---- epilogue2: out = acc + bp (fire-and-forget stores) ----
#pragma unroll
    for (int m = 0; m < 2; ++m) {
#pragma unroll
      for (int n = 0; n < 3; ++n) {
        int col = wv * 48 + n * 16 + (lane & 15);
        float bpv = bp_l[col];
#pragma unroll
        for (int r = 0; r < 4; ++r) {
          int row = m * 16 + (lane >> 4) * 4 + r;
          out[(blockRow0 + (size_t)t * 32 + row) * C_ + col] = acc[m][n][r] + bpv;
        }
      }
    }

    // ---- stage next tile into the other buffer ----
    if (t < 7) { STAGET(cur ^ 1); }
    __syncthreads();
  }
#undef LOADT
#undef STAGET
}

extern "C" void kernel_launch(void* const* d_in, const int* in_sizes, int n_in,
                              void* d_out, int out_size, void* d_ws, size_t ws_size,
                              hipStream_t stream) {
  const float* x      = (const float*)d_in[0];
  const float* w_qkv  = (const float*)d_in[1];
  const float* b_qkv  = (const float*)d_in[2];
  const float* w_proj = (const float*)d_in[3];
  const float* b_proj = (const float*)d_in[4];
  float* out = (float*)d_out;

  // ws: xsum[128*384 f] | cv[128*384 f] | pWv[147456 bf16] | pWp[147456 bf16]  (~1 MB)
  float* xsum = (float*)d_ws;
  float* cvp  = xsum + G_ * C_;
  unsigned short* pWv = (unsigned short*)(cvp + G_ * C_);
  unsigned short* pWp = pWv + C_ * C_;

  hipMemsetAsync(xsum, 0, G_ * C_ * sizeof(float), stream);
  k_xsum<<<1024, 384, 0, stream>>>(x, xsum);        // also warms L3 with x
  k_pack<<<576, 64, 0, stream>>>(w_qkv, w_proj, pWv, pWp);
  k_cv<<<G_, C_, 0, stream>>>(xsum, w_qkv, b_qkv, cvp);
  k_fused<<<512, 512, 0, stream>>>(x, pWv, pWp, cvp, b_qkv, b_proj, out);
}

// Round 4
// 905.590 us; speedup vs baseline: 1.0192x; 1.0192x over previous
//
#include <hip/hip_runtime.h>
#include <hip/hip_bf16.h>
#include <type_traits>
#include <utility>

// Problem: B=32, P=4, N=1024, C=384.
// softmax over a size-1 axis == 1.0, so:
//   cv[b,p,:]  = (sum_n x[b,p,n,:]) @ Wk + N*bk          (fp32, exact)
//   out        = (relu(x@Wv + bv) * cv) @ Wp + bp        (bf16 MFMA, fused)
#define C_    384
#define N_    1024
#define G_    128          // B*P groups
#define QKVD  769

typedef float  f32x4 __attribute__((ext_vector_type(4)));
typedef short  s16x8 __attribute__((ext_vector_type(8)));
typedef __bf16 b16x8 __attribute__((ext_vector_type(8)));

template <typename V, typename = void>
struct mfma_takes : std::false_type {};
template <typename V>
struct mfma_takes<V, std::void_t<decltype(__builtin_amdgcn_mfma_f32_16x16x32_bf16(
    std::declval<V>(), std::declval<V>(), std::declval<f32x4>(), 0, 0, 0))>>
    : std::true_type {};

using frag_t = std::conditional_t<mfma_takes<s16x8>::value, s16x8, b16x8>;

template <typename V>
__device__ __forceinline__ f32x4 mfma_bf16(V a, V b, f32x4 c) {
  return __builtin_amdgcn_mfma_f32_16x16x32_bf16(a, b, c, 0, 0, 0);
}

__device__ __forceinline__ unsigned short f2bf(float f) {
  union { float f; unsigned u; } v; v.f = f;
  unsigned r = v.u + 0x7fffu + ((v.u >> 16) & 1u);   // RNE
  return (unsigned short)(r >> 16);
}
__device__ __forceinline__ unsigned pack2(float lo, float hi) {
  return (unsigned)f2bf(lo) | ((unsigned)f2bf(hi) << 16);
}

// ---------------- K1: xsum[g][c] = sum_n x[g][n][c]  (float4, LDS-reduced) ----------------
__global__ __launch_bounds__(384) void k_xsum(const float* __restrict__ x,
                                              float* __restrict__ xsum) {
  __shared__ float sh[4][C_];
  const int tid = threadIdx.x;
  const int c4  = (tid % 96) * 4;
  const int rg  = tid / 96;            // 0..3
  const int b   = blockIdx.x;          // 1024
  const int g   = b >> 3;
  const float* p = x + ((size_t)b * 128 + (size_t)rg * 32) * C_ + c4;
  f32x4 s = {0.f, 0.f, 0.f, 0.f};
#pragma unroll 8
  for (int r = 0; r < 32; ++r) {
    float4 v = *(const float4*)(p + (size_t)r * C_);
    s.x += v.x; s.y += v.y; s.z += v.z; s.w += v.w;
  }
  *(f32x4*)&sh[rg][c4] = s;
  __syncthreads();
  if (rg == 0) {
#pragma unroll
    for (int j = 0; j < 4; ++j) {
      float v = sh[0][c4 + j] + sh[1][c4 + j] + sh[2][c4 + j] + sh[3][c4 + j];
      atomicAdd(&xsum[g * C_ + c4 + j], v);
    }
  }
}

// ---------------- K2: cv[g][c] = xsum[g]@Wk[:,c] + N*bk[c] ----------------
__global__ void k_cv(const float* __restrict__ xsum, const float* __restrict__ w_qkv,
                     const float* __restrict__ b_qkv, float* __restrict__ cv) {
  __shared__ float xs[C_];
  int g = blockIdx.x, c = threadIdx.x;   // 384 threads
  xs[c] = xsum[g * C_ + c];
  __syncthreads();
  float acc = 0.f;
#pragma unroll 4
  for (int k = 0; k < C_; ++k) acc += xs[k] * w_qkv[k * QKVD + 1 + c];
  cv[g * C_ + c] = acc + (float)N_ * b_qkv[1 + c];
}

// ------- K3: pack Wv (w_qkv[:,385:769]) and Wp (w_proj) as bf16 frag-major -------
// entry (kk,nf,lane) -> 8 bf16 = B[k = kk*32+(lane>>4)*8 + j][n = nf*16+(lane&15)]
__global__ void k_pack(const float* __restrict__ w_qkv, const float* __restrict__ w_proj,
                       unsigned short* __restrict__ pWv, unsigned short* __restrict__ pWp) {
  int bid = blockIdx.x;
  int mat = bid / 288;             // 0: Wv, 1: Wp    (288 = 12 kk * 24 nf)
  int r   = bid % 288;
  int kk = r / 24, nf = r % 24;
  int lane = threadIdx.x;          // 64
  int kbase = kk * 32 + (lane >> 4) * 8;
  int n = nf * 16 + (lane & 15);
  unsigned v[4];
#pragma unroll
  for (int jj = 0; jj < 4; ++jj) {
    int k0 = kbase + jj * 2;
    float f0 = mat ? w_proj[(size_t)k0 * C_ + n]       : w_qkv[(size_t)k0 * QKVD + 385 + n];
    float f1 = mat ? w_proj[(size_t)(k0 + 1) * C_ + n] : w_qkv[(size_t)(k0 + 1) * QKVD + 385 + n];
    v[jj] = (unsigned)f2bf(f0) | ((unsigned)f2bf(f1) << 16);
  }
  unsigned short* dst = (mat ? pWp : pWv) + ((size_t)r * 64 + lane) * 8;
  uint4 w; w.x = v[0]; w.y = v[1]; w.z = v[2]; w.w = v[3];
  *(uint4*)dst = w;
}

// ---------------- K4: fused value-GEMM -> relu*cv -> proj-GEMM ----------------
// 4096 blocks x 256 thr (4 waves). Block = 32 rows x 384 cols.
// Wave w: all 32 rows x cols [w*96, w*96+96); n-dim done in two halves of 3 frags
// to keep live VGPRs low (acc 48 + A 8 + Bv 12).
__global__ __launch_bounds__(256, 2) void k_fused(
    const float* __restrict__ x, const unsigned short* __restrict__ pWv,
    const unsigned short* __restrict__ pWp, const float* __restrict__ cv,
    const float* __restrict__ b_qkv, const float* __restrict__ b_proj,
    float* __restrict__ out) {
  __shared__ __align__(16) char tile[32 * 768];   // 32 rows x 384 bf16, XOR-swizzled
  __shared__ float cv_l[C_], bv_l[C_], bp_l[C_];

  const int tid  = threadIdx.x;
  const int lane = tid & 63;
  const int wv   = tid >> 6;                 // 0..3
  const int R0   = blockIdx.x * 32;
  const int g    = R0 >> 10;

  for (int c = tid; c < C_; c += 256) {
    cv_l[c] = cv[g * C_ + c];
    bv_l[c] = b_qkv[1 + C_ + c];
    bp_l[c] = b_proj[c];
  }

  // stage 32x384 fp32 -> bf16 -> LDS (swizzle: byte off ^= (row&7)<<4)
  {
    const float* xg = x + (size_t)R0 * C_;
#pragma unroll
    for (int j = 0; j < 6; ++j) {
      int ch  = tid + j * 256;          // 1536 chunks of 8 f32
      int row = ch / 48;
      int c8  = (ch % 48) * 8;          // element col
      const float4* s0 = (const float4*)(xg + (size_t)row * C_ + c8);
      float4 a = s0[0], b = s0[1];
      uint4 w;
      w.x = pack2(a.x, a.y); w.y = pack2(a.z, a.w);
      w.z = pack2(b.x, b.y); w.w = pack2(b.z, b.w);
      int byte = (row * 768 + c8 * 2) ^ ((row & 7) << 4);
      *(uint4*)(tile + byte) = w;
    }
  }
  __syncthreads();

  const f32x4 zero = {0.f, 0.f, 0.f, 0.f};
  f32x4 acc[2][6];
#pragma unroll
  for (int m = 0; m < 2; ++m)
#pragma unroll
    for (int n = 0; n < 6; ++n) acc[m][n] = zero;

  // ---- GEMM1: value = x @ Wv ----  (n in two halves of 3, A reloaded per half)
#pragma unroll 1
  for (int h = 0; h < 2; ++h) {
    for (int kk = 0; kk < 12; ++kk) {
      frag_t A[2], Bv[3];
      int kb2 = (kk * 32 + (lane >> 4) * 8) * 2;
#pragma unroll
      for (int m = 0; m < 2; ++m) {
        int row = m * 16 + (lane & 15);
        A[m] = *(const frag_t*)(tile + ((row * 768 + kb2) ^ ((row & 7) << 4)));
      }
      const unsigned short* bp_ = pWv + ((size_t)(kk * 24 + wv * 6 + h * 3) * 64 + lane) * 8;
#pragma unroll
      for (int n = 0; n < 3; ++n) Bv[n] = *(const frag_t*)(bp_ + (size_t)n * 64 * 8);
#pragma unroll
      for (int m = 0; m < 2; ++m)
#pragma unroll
        for (int n = 0; n < 3; ++n)
          acc[m][h * 3 + n] = mfma_bf16(A[m], Bv[n], acc[m][h * 3 + n]);
    }
  }
  __syncthreads();   // all waves done reading x tile

  // ---- epilogue1: gated = relu(value + bv) * cv -> bf16 -> same LDS tile ----
#pragma unroll
  for (int m = 0; m < 2; ++m) {
#pragma unroll
    for (int n = 0; n < 6; ++n) {
      int col = wv * 96 + n * 16 + (lane & 15);
      float cvv = cv_l[col], bvv = bv_l[col];
#pragma unroll
      for (int r = 0; r < 4; ++r) {
        int row = m * 16 + (lane >> 4) * 4 + r;   // verified C/D layout
        float val = fmaxf(acc[m][n][r] + bvv, 0.f) * cvv;
        *(unsigned short*)(tile + ((row * 768 + col * 2) ^ ((row & 7) << 4))) = f2bf(val);
      }
    }
  }
  __syncthreads();   // gated tile complete

  // ---- GEMM2: out = gated @ Wp ----
#pragma unroll
  for (int m = 0; m < 2; ++m)
#pragma unroll
    for (int n = 0; n < 6; ++n) acc[m][n] = zero;

#pragma unroll 1
  for (int h = 0; h < 2; ++h) {
    for (int kk = 0; kk < 12; ++kk) {
      frag_t A[2], Bv[3];
      int kb2 = (kk * 32 + (lane >> 4) * 8) * 2;
#pragma unroll
      for (int m = 0; m < 2; ++m) {
        int row = m * 16 + (lane & 15);
        A[m] = *(const frag_t*)(tile + ((row * 768 + kb2) ^ ((row & 7) << 4)));
      }
      const unsigned short* bp_ = pWp + ((size_t)(kk * 24 + wv * 6 + h * 3) * 64 + lane) * 8;
#pragma unroll
      for (int n = 0; n < 3; ++n) Bv[n] = *(const frag_t*)(bp_ + (size_t)n * 64 * 8);
#pragma unroll
      for (int m = 0; m < 2; ++m)
#pragma unroll
        for (int n = 0; n < 3; ++n)
          acc[m][h * 3 + n] = mfma_bf16(A[m], Bv[n], acc[m][h * 3 + n]);
    }
  }

  // ---- epilogue2: out = acc + bp ----
#pragma unroll
  for (int m = 0; m < 2; ++m) {
#pragma unroll
    for (int n = 0; n < 6; ++n) {
      int col = wv * 96 + n * 16 + (lane & 15);
      float bpv = bp_l[col];
#pragma unroll
      for (int r = 0; r < 4; ++r) {
        int row = m * 16 + (lane >> 4) * 4 + r;
        out[(size_t)(R0 + row) * C_ + col] = acc[m][n][r] + bpv;
      }
    }
  }
}

extern "C" void kernel_launch(void* const* d_in, const int* in_sizes, int n_in,
                              void* d_out, int out_size, void* d_ws, size_t ws_size,
                              hipStream_t stream) {
  const float* x      = (const float*)d_in[0];
  const float* w_qkv  = (const float*)d_in[1];
  const float* b_qkv  = (const float*)d_in[2];
  const float* w_proj = (const float*)d_in[3];
  const float* b_proj = (const float*)d_in[4];
  float* out = (float*)d_out;

  // ws: xsum[128*384 f] | cv[128*384 f] | pWv[147456 bf16] | pWp[147456 bf16]  (~1 MB)
  float* xsum = (float*)d_ws;
  float* cvp  = xsum + G_ * C_;
  unsigned short* pWv = (unsigned short*)(cvp + G_ * C_);
  unsigned short* pWp = pWv + C_ * C_;

  hipMemsetAsync(xsum, 0, G_ * C_ * sizeof(float), stream);
  k_xsum<<<1024, 384, 0, stream>>>(x, xsum);        // also warms L3 with x
  k_pack<<<576, 64, 0, stream>>>(w_qkv, w_proj, pWv, pWp);
  k_cv<<<G_, C_, 0, stream>>>(xsum, w_qkv, b_qkv, cvp);
  k_fused<<<4096, 256, 0, stream>>>(x, pWv, pWp, cvp, b_qkv, b_proj, out);
}

// Round 5
// 228.890 us; speedup vs baseline: 4.0325x; 3.9564x over previous
//
#include <hip/hip_runtime.h>
#include <hip/hip_bf16.h>
#include <type_traits>
#include <utility>

// Problem: B=32, P=4, N=1024, C=384.
// softmax over a size-1 axis == 1.0, so:
//   cv[b,p,:]  = (sum_n x[b,p,n,:]) @ Wk + N*bk          (fp32, exact)
//   out        = (relu(x@Wv + bv) * cv) @ Wp + bp        (bf16 MFMA, fused)
#define C_    384
#define N_    1024
#define G_    128          // B*P groups
#define QKVD  769

typedef float  f32x4 __attribute__((ext_vector_type(4)));
typedef short  s16x8 __attribute__((ext_vector_type(8)));
typedef __bf16 b16x8 __attribute__((ext_vector_type(8)));

template <typename V, typename = void>
struct mfma_takes : std::false_type {};
template <typename V>
struct mfma_takes<V, std::void_t<decltype(__builtin_amdgcn_mfma_f32_16x16x32_bf16(
    std::declval<V>(), std::declval<V>(), std::declval<f32x4>(), 0, 0, 0))>>
    : std::true_type {};

using frag_t = std::conditional_t<mfma_takes<s16x8>::value, s16x8, b16x8>;

template <typename V>
__device__ __forceinline__ f32x4 mfma_bf16(V a, V b, f32x4 c) {
  return __builtin_amdgcn_mfma_f32_16x16x32_bf16(a, b, c, 0, 0, 0);
}

__device__ __forceinline__ unsigned short f2bf(float f) {
  union { float f; unsigned u; } v; v.f = f;
  unsigned r = v.u + 0x7fffu + ((v.u >> 16) & 1u);   // RNE
  return (unsigned short)(r >> 16);
}
__device__ __forceinline__ unsigned pack2(float lo, float hi) {
  return (unsigned)f2bf(lo) | ((unsigned)f2bf(hi) << 16);
}

// ---------------- K1: xsum[g][c] = sum_n x[g][n][c]  (float4, LDS-reduced) ----------------
__global__ __launch_bounds__(384) void k_xsum(const float* __restrict__ x,
                                              float* __restrict__ xsum) {
  __shared__ float sh[4][C_];
  const int tid = threadIdx.x;
  const int c4  = (tid % 96) * 4;
  const int rg  = tid / 96;            // 0..3
  const int b   = blockIdx.x;          // 1024
  const int g   = b >> 3;
  const float* p = x + ((size_t)b * 128 + (size_t)rg * 32) * C_ + c4;
  f32x4 s = {0.f, 0.f, 0.f, 0.f};
#pragma unroll 8
  for (int r = 0; r < 32; ++r) {
    float4 v = *(const float4*)(p + (size_t)r * C_);
    s.x += v.x; s.y += v.y; s.z += v.z; s.w += v.w;
  }
  *(f32x4*)&sh[rg][c4] = s;
  __syncthreads();
  if (rg == 0) {
#pragma unroll
    for (int j = 0; j < 4; ++j) {
      float v = sh[0][c4 + j] + sh[1][c4 + j] + sh[2][c4 + j] + sh[3][c4 + j];
      atomicAdd(&xsum[g * C_ + c4 + j], v);
    }
  }
}

// ---------------- K2: cv[g][c] = xsum[g]@Wk[:,c] + N*bk[c] ----------------
__global__ void k_cv(const float* __restrict__ xsum, const float* __restrict__ w_qkv,
                     const float* __restrict__ b_qkv, float* __restrict__ cv) {
  __shared__ float xs[C_];
  int g = blockIdx.x, c = threadIdx.x;   // 384 threads
  xs[c] = xsum[g * C_ + c];
  __syncthreads();
  float acc = 0.f;
#pragma unroll 4
  for (int k = 0; k < C_; ++k) acc += xs[k] * w_qkv[k * QKVD + 1 + c];
  cv[g * C_ + c] = acc + (float)N_ * b_qkv[1 + c];
}

// ------- K3: pack Wv (w_qkv[:,385:769]) and Wp (w_proj) as bf16 frag-major -------
// entry (kk,nf,lane) -> 8 bf16 = B[k = kk*32+(lane>>4)*8 + j][n = nf*16+(lane&15)]
__global__ void k_pack(const float* __restrict__ w_qkv, const float* __restrict__ w_proj,
                       unsigned short* __restrict__ pWv, unsigned short* __restrict__ pWp) {
  int bid = blockIdx.x;
  int mat = bid / 288;             // 0: Wv, 1: Wp    (288 = 12 kk * 24 nf)
  int r   = bid % 288;
  int kk = r / 24, nf = r % 24;
  int lane = threadIdx.x;          // 64
  int kbase = kk * 32 + (lane >> 4) * 8;
  int n = nf * 16 + (lane & 15);
  unsigned v[4];
#pragma unroll
  for (int jj = 0; jj < 4; ++jj) {
    int k0 = kbase + jj * 2;
    float f0 = mat ? w_proj[(size_t)k0 * C_ + n]       : w_qkv[(size_t)k0 * QKVD + 385 + n];
    float f1 = mat ? w_proj[(size_t)(k0 + 1) * C_ + n] : w_qkv[(size_t)(k0 + 1) * QKVD + 385 + n];
    v[jj] = (unsigned)f2bf(f0) | ((unsigned)f2bf(f1) << 16);
  }
  unsigned short* dst = (mat ? pWp : pWv) + ((size_t)r * 64 + lane) * 8;
  uint4 w; w.x = v[0]; w.y = v[1]; w.z = v[2]; w.w = v[3];
  *(uint4*)dst = w;
}

// ---------------- K4: fused value-GEMM -> relu*cv -> proj-GEMM ----------------
// 4096 blocks x 256 thr (4 waves). Block = 32 rows x 384 cols.
// Wave w: all 32 rows x cols [w*96, w*96+96). ALL register indices compile-time
// (rule #20: runtime-indexed ext_vector arrays go to scratch).
__global__ __launch_bounds__(256) void k_fused(
    const float* __restrict__ x, const unsigned short* __restrict__ pWv,
    const unsigned short* __restrict__ pWp, const float* __restrict__ cv,
    const float* __restrict__ b_qkv, const float* __restrict__ b_proj,
    float* __restrict__ out) {
  __shared__ __align__(16) char tile[32 * 768];   // 32 rows x 384 bf16, XOR-swizzled
  __shared__ float cv_l[C_], bv_l[C_], bp_l[C_];

  const int tid  = threadIdx.x;
  const int lane = tid & 63;
  const int wv   = tid >> 6;                 // 0..3
  const int R0   = blockIdx.x * 32;
  const int g    = R0 >> 10;

  for (int c = tid; c < C_; c += 256) {
    cv_l[c] = cv[g * C_ + c];
    bv_l[c] = b_qkv[1 + C_ + c];
    bp_l[c] = b_proj[c];
  }

  // stage 32x384 fp32 -> bf16 -> LDS (swizzle: byte off ^= (row&7)<<4)
  {
    const float* xg = x + (size_t)R0 * C_;
#pragma unroll
    for (int j = 0; j < 6; ++j) {
      int ch  = tid + j * 256;          // 1536 chunks of 8 f32
      int row = ch / 48;
      int c8  = (ch % 48) * 8;          // element col
      const float4* s0 = (const float4*)(xg + (size_t)row * C_ + c8);
      float4 a = s0[0], b = s0[1];
      uint4 w;
      w.x = pack2(a.x, a.y); w.y = pack2(a.z, a.w);
      w.z = pack2(b.x, b.y); w.w = pack2(b.z, b.w);
      int byte = (row * 768 + c8 * 2) ^ ((row & 7) << 4);
      *(uint4*)(tile + byte) = w;
    }
  }
  __syncthreads();

  const f32x4 zero = {0.f, 0.f, 0.f, 0.f};
  f32x4 acc[2][6];
#pragma unroll
  for (int m = 0; m < 2; ++m)
#pragma unroll
    for (int n = 0; n < 6; ++n) acc[m][n] = zero;

  // ---- GEMM1: value = x @ Wv ----
  for (int kk = 0; kk < 12; ++kk) {
    frag_t A[2], Bv[6];
    int kb2 = (kk * 32 + (lane >> 4) * 8) * 2;
#pragma unroll
    for (int m = 0; m < 2; ++m) {
      int row = m * 16 + (lane & 15);
      A[m] = *(const frag_t*)(tile + ((row * 768 + kb2) ^ ((row & 7) << 4)));
    }
    const unsigned short* bp_ = pWv + ((size_t)(kk * 24 + wv * 6) * 64 + lane) * 8;
#pragma unroll
    for (int n = 0; n < 6; ++n) Bv[n] = *(const frag_t*)(bp_ + (size_t)n * 64 * 8);
#pragma unroll
    for (int m = 0; m < 2; ++m)
#pragma unroll
      for (int n = 0; n < 6; ++n) acc[m][n] = mfma_bf16(A[m], Bv[n], acc[m][n]);
  }
  __syncthreads();   // all waves done reading x tile

  // ---- epilogue1: gated = relu(value + bv) * cv -> bf16 -> same LDS tile ----
#pragma unroll
  for (int m = 0; m < 2; ++m) {
#pragma unroll
    for (int n = 0; n < 6; ++n) {
      int col = wv * 96 + n * 16 + (lane & 15);
      float cvv = cv_l[col], bvv = bv_l[col];
#pragma unroll
      for (int r = 0; r < 4; ++r) {
        int row = m * 16 + (lane >> 4) * 4 + r;   // verified C/D layout
        float val = fmaxf(acc[m][n][r] + bvv, 0.f) * cvv;
        *(unsigned short*)(tile + ((row * 768 + col * 2) ^ ((row & 7) << 4))) = f2bf(val);
      }
    }
  }
  __syncthreads();   // gated tile complete

  // ---- GEMM2: out = gated @ Wp ----
#pragma unroll
  for (int m = 0; m < 2; ++m)
#pragma unroll
    for (int n = 0; n < 6; ++n) acc[m][n] = zero;

  for (int kk = 0; kk < 12; ++kk) {
    frag_t A[2], Bv[6];
    int kb2 = (kk * 32 + (lane >> 4) * 8) * 2;
#pragma unroll
    for (int m = 0; m < 2; ++m) {
      int row = m * 16 + (lane & 15);
      A[m] = *(const frag_t*)(tile + ((row * 768 + kb2) ^ ((row & 7) << 4)));
    }
    const unsigned short* bp_ = pWp + ((size_t)(kk * 24 + wv * 6) * 64 + lane) * 8;
#pragma unroll
    for (int n = 0; n < 6; ++n) Bv[n] = *(const frag_t*)(bp_ + (size_t)n * 64 * 8);
#pragma unroll
    for (int m = 0; m < 2; ++m)
#pragma unroll
      for (int n = 0; n < 6; ++n) acc[m][n] = mfma_bf16(A[m], Bv[n], acc[m][n]);
  }

  // ---- epilogue2: out = acc + bp ----
#pragma unroll
  for (int m = 0; m < 2; ++m) {
#pragma unroll
    for (int n = 0; n < 6; ++n) {
      int col = wv * 96 + n * 16 + (lane & 15);
      float bpv = bp_l[col];
#pragma unroll
      for (int r = 0; r < 4; ++r) {
        int row = m * 16 + (lane >> 4) * 4 + r;
        out[(size_t)(R0 + row) * C_ + col] = acc[m][n][r] + bpv;
      }
    }
  }
}

extern "C" void kernel_launch(void* const* d_in, const int* in_sizes, int n_in,
                              void* d_out, int out_size, void* d_ws, size_t ws_size,
                              hipStream_t stream) {
  const float* x      = (const float*)d_in[0];
  const float* w_qkv  = (const float*)d_in[1];
  const float* b_qkv  = (const float*)d_in[2];
  const float* w_proj = (const float*)d_in[3];
  const float* b_proj = (const float*)d_in[4];
  float* out = (float*)d_out;

  // ws: xsum[128*384 f] | cv[128*384 f] | pWv[147456 bf16] | pWp[147456 bf16]  (~1 MB)
  float* xsum = (float*)d_ws;
  float* cvp  = xsum + G_ * C_;
  unsigned short* pWv = (unsigned short*)(cvp + G_ * C_);
  unsigned short* pWp = pWv + C_ * C_;

  hipMemsetAsync(xsum, 0, G_ * C_ * sizeof(float), stream);
  k_xsum<<<1024, 384, 0, stream>>>(x, xsum);        // also warms L3 with x
  k_pack<<<576, 64, 0, stream>>>(w_qkv, w_proj, pWv, pWp);
  k_cv<<<G_, C_, 0, stream>>>(xsum, w_qkv, b_qkv, cvp);
  k_fused<<<4096, 256, 0, stream>>>(x, pWv, pWp, cvp, b_qkv, b_proj, out);
}